// Round 12
// baseline (176.390 us; speedup 1.0000x reference)
//
#include <hip/hip_runtime.h>

typedef __attribute__((ext_vector_type(4))) float f32x4;
typedef __attribute__((ext_vector_type(16))) float f32x16;
typedef __attribute__((ext_vector_type(8))) short short8;

#define DEV static __device__ __forceinline__

DEV unsigned short f2bf(float f) {
  union { float f; unsigned u; } x; x.f = f;
  unsigned r = x.u + 0x7fffu + ((x.u >> 16) & 1u);
  return (unsigned short)(r >> 16);
}

DEV float bf2f(unsigned short u) {
  union { unsigned u; float f; } x; x.u = ((unsigned)u) << 16;
  return x.f;
}

DEV f32x4 mfma16(short8 a, short8 b, f32x4 c) {
  return __builtin_amdgcn_mfma_f32_16x16x32_bf16(a, b, c, 0, 0, 0);
}

DEV f32x16 mfma32(short8 a, short8 b, f32x16 c) {
  return __builtin_amdgcn_mfma_f32_32x32x16_bf16(a, b, c, 0, 0, 0);
}

DEV void gload16(const void* g, void* l) {
  __builtin_amdgcn_global_load_lds(
      (const __attribute__((address_space(1))) void*)g,
      (__attribute__((address_space(3))) void*)l, 16, 0, 0);
}

DEV float exp2f_fast(float x) {
  float r;
  asm("v_exp_f32 %0, %1" : "=v"(r) : "v"(x));
  return r;
}

DEV unsigned cvtpk(float lo, float hi) {
  unsigned r;
  asm("v_cvt_pk_bf16_f32 %0, %1, %2" : "=v"(r) : "v"(lo), "v"(hi));
  return r;
}

DEV short8 mk8(unsigned w0, unsigned w1, unsigned w2, unsigned w3) {
  union { unsigned u[4]; short8 s; } x;
  x.u[0] = w0; x.u[1] = w1; x.u[2] = w2; x.u[3] = w3;
  return x.s;
}

// two-level LDS swizzle (r10: verified BANK_CONFLICT 4.2M -> 0)
DEV int swzrow(int r) { return (((r & 7) ^ ((r >> 3) & 7)) << 3); }

// ---------------- fused prep: x->bf16, both weight transposes ----------------
__global__ __launch_bounds__(256) void k_prep(
    const float* __restrict__ x, unsigned short* __restrict__ xb,
    const float* __restrict__ wq, unsigned short* __restrict__ wqT,
    const float* __restrict__ wo, unsigned short* __restrict__ woT) {
  __shared__ unsigned short T[64 * 72];
  const int blk = blockIdx.x;
  const int t = threadIdx.x;
  if (blk < 2048) {
    size_t i = (size_t)blk * 256 + t;
    const f32x4* p = (const f32x4*)(x + i * 8);
    f32x4 a = p[0], b = p[1];
    short8 r;
    r[0] = f2bf(a[0]); r[1] = f2bf(a[1]); r[2] = f2bf(a[2]); r[3] = f2bf(a[3]);
    r[4] = f2bf(b[0]); r[5] = f2bf(b[1]); r[6] = f2bf(b[2]); r[7] = f2bf(b[3]);
    *(short8*)(xb + i * 8) = r;
    return;
  }
  const float* in;
  unsigned short* out;
  int C, bx, by;
  const int R = 512;
  if (blk < 2240) {
    in = wq; out = wqT; C = 1536;
    int bb = blk - 2048; bx = bb % 24; by = bb / 24;
  } else {
    in = wo; out = woT; C = 512;
    int bb = blk - 2240; bx = bb & 7; by = bb >> 3;
  }
  int r0 = by * 64, c0 = bx * 64;
  int rr = t >> 2, seg = t & 3;
  const float* p = in + (size_t)(r0 + rr) * C + c0 + seg * 16;
#pragma unroll
  for (int q = 0; q < 4; ++q) {
    f32x4 v = *(const f32x4*)(p + q * 4);
#pragma unroll
    for (int e = 0; e < 4; ++e) T[rr * 72 + seg * 16 + q * 4 + e] = f2bf(v[e]);
  }
  __syncthreads();
  short8 o0, o1;
#pragma unroll
  for (int e = 0; e < 8; ++e) o0[e] = (short)T[(seg * 16 + e) * 72 + rr];
#pragma unroll
  for (int e = 0; e < 8; ++e) o1[e] = (short)T[(seg * 16 + 8 + e) * 72 + rr];
  unsigned short* q2 = out + (size_t)(c0 + rr) * R + r0 + seg * 16;
  *(short8*)q2 = o0;
  *(short8*)(q2 + 8) = o1;
}

// ---------------- GEMM: C[M][N] = A[M][K] * Bt[N][K]^T (+bias) ----------------
// NT: N-tile. WVT: V-column blocks (bn>=1024) write transposed vt directly.
template <bool F32OUT, int NT, bool WVT>
__global__ __launch_bounds__(256) void k_gemm_bt(
    const unsigned short* __restrict__ A, const unsigned short* __restrict__ Bt,
    void* __restrict__ Cp, const float* __restrict__ bias,
    unsigned short* __restrict__ vt, int M, int N, int K) {
  constexpr int NJ = NT / 32;
  constexpr int SHSZ = WVT ? (128 * 136) : (8192 + NT * 64);
  __shared__ unsigned short SH[SHSZ];
  unsigned short* Asm = SH;
  unsigned short* Bsm = SH + 8192;
  const int tid = threadIdx.x;
  const int lane = tid & 63, w = tid >> 6;
  const int wr = w >> 1, wc = w & 1;
  const int nbx = gridDim.x;
  const int cpx = (nbx * gridDim.y) >> 3;
  const int lin = blockIdx.y * nbx + blockIdx.x;
  const int swz = (lin & 7) * cpx + (lin >> 3);
  const int bm = (swz / nbx) * 128, bn = (swz % nbx) * NT;
  const int l15 = lane & 15, l4 = lane >> 4;
  f32x4 acc[4][NJ] = {};
  for (int k0 = 0; k0 < K; k0 += 64) {
    __syncthreads();
#pragma unroll
    for (int j = 0; j < 4; ++j) {
      int c = j * 256 + tid;
      gload16(A + (size_t)(bm + (c >> 3)) * K + k0 + ((c & 7) << 3),
              Asm + (size_t)(j * 256 + w * 64) * 8);
    }
#pragma unroll
    for (int j = 0; j < NJ; ++j) {
      int c = j * 256 + tid;
      gload16(Bt + (size_t)(bn + (c >> 3)) * K + k0 + ((c & 7) << 3),
              Bsm + (size_t)(j * 256 + w * 64) * 8);
    }
    __syncthreads();
#pragma unroll
    for (int kc = 0; kc < 2; ++kc) {
      short8 av[4], bv[NJ];
#pragma unroll
      for (int i = 0; i < 4; ++i)
        av[i] = *(const short8*)&Asm[(wr * 64 + i * 16 + l15) * 64 + kc * 32 + l4 * 8];
#pragma unroll
      for (int j = 0; j < NJ; ++j)
        bv[j] = *(const short8*)&Bsm[(wc * (NT / 2) + j * 16 + l15) * 64 + kc * 32 + l4 * 8];
#pragma unroll
      for (int i = 0; i < 4; ++i)
#pragma unroll
        for (int j = 0; j < NJ; ++j)
          acc[i][j] = mfma16(av[i], bv[j], acc[i][j]);
    }
  }
  if (WVT && bn >= 1024) {
    __syncthreads();
#pragma unroll
    for (int i = 0; i < 4; ++i)
#pragma unroll
      for (int j = 0; j < NJ; ++j) {
        int colL = wc * (NT / 2) + j * 16 + l15;
#pragma unroll
        for (int v = 0; v < 4; ++v)
          SH[colL * 136 + wr * 64 + i * 16 + l4 * 4 + v] = f2bf(acc[i][j][v]);
      }
    __syncthreads();
    const int vtrow = tid >> 1, half2 = tid & 1;
    const int b2 = bm >> 11, npos0 = bm & 2047;
    const int h = ((bn - 1024) >> 6) + (vtrow >> 6);
    const int hd = vtrow & 63;
    unsigned short* dst =
        vt + ((size_t)(b2 * 8 + h) * 64 + hd) * 2048 + npos0 + half2 * 64;
    const unsigned short* srcT = SH + vtrow * 136 + half2 * 64;
#pragma unroll
    for (int e = 0; e < 8; ++e)
      *(short8*)(dst + e * 8) = *(const short8*)(srcT + e * 8);
    return;
  }
#pragma unroll
  for (int i = 0; i < 4; ++i) {
#pragma unroll
    for (int j = 0; j < NJ; ++j) {
      int col = bn + wc * (NT / 2) + j * 16 + l15;
      float bb = 0.f;
      if constexpr (F32OUT) bb = bias[col];
#pragma unroll
      for (int v = 0; v < 4; ++v) {
        int row = bm + wr * 64 + i * 16 + l4 * 4 + v;
        if constexpr (F32OUT) {
          ((float*)Cp)[(size_t)row * N + col] = acc[i][j][v] + bb;
        } else {
          ((unsigned short*)Cp)[(size_t)row * N + col] = f2bf(acc[i][j][v]);
        }
      }
    }
  }
}

// ---------------- flash attention: 2 tiles/barrier, hoisted addressing -------
// grid (N/128, B*H), 512 threads, KV-half-split (r9-verified layouts).
// 4-deep K/V buffers: iteration i consumes tiles 2i,2i+1 and stages 2i+2,2i+3;
// ONE barrier per 2 tiles (was 1/tile). All LDS frag offsets + global prefetch
// pointers hoisted/incremental (kills per-tile 64-bit mults).
__global__ __launch_bounds__(512, 4) void k_attn6(const unsigned short* __restrict__ qkv,
                                                  const unsigned short* __restrict__ vtg,
                                                  unsigned short* __restrict__ O) {
  __shared__ unsigned short smem[33792];  // K[4][4096] | V[4][4096] | 2KB ml
  const int tid = threadIdx.x;
  const int lane = tid & 63, w = tid >> 6;
  const int qg = w & 3, half = w >> 2;
  const int l31 = lane & 31, hi = lane >> 5;
  const int bh = blockIdx.y, b = bh >> 3, h = bh & 7;
  const int q0 = blockIdx.x * 128 + qg * 32;
  const float CL = 0.044194173824159216f * 1.4426950408889634f;  // SCALE*log2(e)

  short8 qf[4];
  {
    const unsigned short* qp = qkv + (size_t)(b * 2048 + q0 + l31) * 1536 + h * 64;
#pragma unroll
    for (int ks = 0; ks < 4; ++ks) {
      short8 raw = *(const short8*)(qp + ks * 16 + hi * 8);
      short8 f;
#pragma unroll
      for (int e = 0; e < 8; ++e)
        f[e] = (short)f2bf(bf2f((unsigned short)raw[e]) * CL);
      qf[ks] = f;
    }
  }

  const int sr = tid >> 3, seg = tid & 7;
  const unsigned short* kg =
      qkv + (size_t)b * 2048 * 1536 + 512 + h * 64 + (size_t)sr * 1536 + seg * 8;
  const unsigned short* vg =
      vtg + (size_t)bh * 64 * 2048 + (size_t)sr * 2048 + seg * 8;
  const int so = sr * 64 + ((seg * 8) ^ swzrow(sr));

  unsigned short* K0 = smem;          unsigned short* K1 = smem + 4096;
  unsigned short* K2 = smem + 8192;   unsigned short* K3 = smem + 12288;
  unsigned short* V0 = smem + 16384;  unsigned short* V1 = smem + 20480;
  unsigned short* V2 = smem + 24576;  unsigned short* V3 = smem + 28672;

  // prologue: stage tiles 0,1
  *(short8*)&K0[so] = *(const short8*)kg;
  *(short8*)&V0[so] = *(const short8*)vg;
  *(short8*)&K1[so] = *(const short8*)(kg + 64 * 1536);
  *(short8*)&V1[so] = *(const short8*)(vg + 64);
  __syncthreads();

  // hoisted fragment offsets (loop-invariant)
  const int kxor = swzrow(half * 32 + l31);
  const int krow = (half * 32 + l31) * 64;
  int kfo[4], vo0[2], vo1[2];
#pragma unroll
  for (int ks = 0; ks < 4; ++ks) kfo[ks] = krow + ((ks * 16 + hi * 8) ^ kxor);
#pragma unroll
  for (int ks = 0; ks < 2; ++ks) {
    int col = (half * 2 + ks) * 16 + hi * 8;
    vo0[ks] = l31 * 64 + (col ^ swzrow(l31));
    vo1[ks] = (32 + l31) * 64 + (col ^ swzrow(32 + l31));
  }

  f32x16 oacc0 = {}, oacc1 = {};
  float m_run = 0.f, l_run = 0.f;

  auto tile = [&](const unsigned short* kb, const unsigned short* vb) {
    f32x16 st = {};
    __builtin_amdgcn_s_setprio(1);
#pragma unroll
    for (int ks = 0; ks < 4; ++ks) {
      short8 kf = *(const short8*)&kb[kfo[ks]];
      st = mfma32(kf, qf[ks], st);
    }
    __builtin_amdgcn_s_setprio(0);

    float tm[8];
#pragma unroll
    for (int r = 0; r < 8; ++r) tm[r] = fmaxf(st[r], st[r + 8]);
    float pm = fmaxf(fmaxf(fmaxf(tm[0], tm[1]), fmaxf(tm[2], tm[3])),
                     fmaxf(fmaxf(tm[4], tm[5]), fmaxf(tm[6], tm[7])));
    pm = fmaxf(pm, __shfl_xor(pm, 32));

    if (!__all(pm <= m_run + 11.5f)) {  // defer-max (rare)
      float mn = fmaxf(m_run, pm);
      float al = exp2f_fast(m_run - mn);
#pragma unroll
      for (int r = 0; r < 16; ++r) {
        int qd = (r & 3) + 8 * (r >> 2) + 4 * hi;
        float a = __shfl(al, qd);
        oacc0[r] *= a;
        oacc1[r] *= a;
      }
      l_run *= al;
      m_run = mn;
    }

    float p[16];
    float la = 0.f, lb = 0.f;
#pragma unroll
    for (int r = 0; r < 8; ++r) { p[r] = exp2f_fast(st[r] - m_run); la += p[r]; }
#pragma unroll
    for (int r = 8; r < 16; ++r) { p[r] = exp2f_fast(st[r] - m_run); lb += p[r]; }
    float lsum = la + lb;
    short8 pa[2];
#pragma unroll
    for (int g = 0; g < 2; ++g) {
      unsigned pkA0 = cvtpk(p[8 * g + 0], p[8 * g + 1]);
      unsigned pkA1 = cvtpk(p[8 * g + 2], p[8 * g + 3]);
      unsigned pkB0 = cvtpk(p[8 * g + 4], p[8 * g + 5]);
      unsigned pkB1 = cvtpk(p[8 * g + 6], p[8 * g + 7]);
      unsigned tA0 = __shfl_xor(pkA0, 32), tA1 = __shfl_xor(pkA1, 32);
      unsigned tB0 = __shfl_xor(pkB0, 32), tB1 = __shfl_xor(pkB1, 32);
      unsigned w0 = hi ? tB0 : pkA0;
      unsigned w1 = hi ? tB1 : pkA1;
      unsigned w2 = hi ? pkB0 : tA0;
      unsigned w3 = hi ? pkB1 : tA1;
      pa[g] = mk8(w0, w1, w2, w3);
    }
    lsum += __shfl_xor(lsum, 32);
    l_run += lsum;

    __builtin_amdgcn_s_setprio(1);
#pragma unroll
    for (int ks = 0; ks < 2; ++ks) {
      short8 vf0 = *(const short8*)&vb[vo0[ks]];
      short8 vf1 = *(const short8*)&vb[vo1[ks]];
      oacc0 = mfma32(pa[ks], vf0, oacc0);
      oacc1 = mfma32(pa[ks], vf1, oacc1);
    }
    __builtin_amdgcn_s_setprio(0);
  };

  unsigned short *cA = K0, *cB = K1, *sA = K2, *sB = K3;
  unsigned short *vA = V0, *vB = V1, *wA = V2, *wB = V3;
  const unsigned short* kgp = kg + 2 * 64 * 1536;
  const unsigned short* vgp = vg + 2 * 64;

  for (int i = 0; i < 16; ++i) {
    short8 pk0, pk1, pv0, pv1;
    const bool more = (i < 15);
    if (more) {
      pk0 = *(const short8*)kgp;
      pk1 = *(const short8*)(kgp + 64 * 1536);
      pv0 = *(const short8*)vgp;
      pv1 = *(const short8*)(vgp + 64);
      kgp += 128 * 1536;
      vgp += 128;
    }
    tile(cA, vA);
    tile(cB, vB);
    if (more) {
      *(short8*)&sA[so] = pk0; *(short8*)&sB[so] = pk1;
      *(short8*)&wA[so] = pv0; *(short8*)&wB[so] = pv1;
    }
    __syncthreads();
    { unsigned short* t1 = cA; cA = sA; sA = t1; }
    { unsigned short* t1 = cB; cB = sB; sB = t1; }
    { unsigned short* t1 = vA; vA = wA; wA = t1; }
    { unsigned short* t1 = vB; vB = wB; wB = t1; }
  }

  // ---- pair combine: half 1 publishes partials, half 0 merges + writes ----
  float* Opart = (float*)smem;            // 32KB, aliases the 4 K buffers
  float* mlbuf = (float*)(smem + 16384);  // V0 region (dead)
  if (half == 1) {
    float* op = Opart + qg * 2048;
#pragma unroll
    for (int r = 0; r < 16; ++r) {
      int qd = (r & 3) + 8 * (r >> 2) + 4 * hi;
      op[qd * 64 + l31] = oacc0[r];
      op[qd * 64 + 32 + l31] = oacc1[r];
    }
    if (hi == 0) {
      mlbuf[qg * 64 + l31] = m_run;
      mlbuf[qg * 64 + 32 + l31] = l_run;
    }
  }
  __syncthreads();
  if (half == 0) {
    float mb = mlbuf[qg * 64 + l31];
    float lb2 = mlbuf[qg * 64 + 32 + l31];
    float mmax = fmaxf(m_run, mb);
    float sa = exp2f_fast(m_run - mmax);
    float sb = exp2f_fast(mb - mmax);
    float dI = 1.0f / (l_run * sa + lb2 * sb);
    float fA = sa * dI, fB = sb * dI;
    const float* op = Opart + qg * 2048;
#pragma unroll
    for (int r = 0; r < 16; ++r) {
      int qd = (r & 3) + 8 * (r >> 2) + 4 * hi;
      float fa = __shfl(fA, qd), fb = __shfl(fB, qd);
      float o0 = oacc0[r] * fa + op[qd * 64 + l31] * fb;
      float o1 = oacc1[r] * fa + op[qd * 64 + 32 + l31] * fb;
      size_t row = (size_t)(b * 2048 + q0 + qd) * 512 + h * 64;
      O[row + l31] = f2bf(o0);
      O[row + 32 + l31] = f2bf(o1);
    }
  }
}

extern "C" void kernel_launch(void* const* d_in, const int* in_sizes, int n_in,
                              void* d_out, int out_size, void* d_ws, size_t ws_size,
                              hipStream_t stream) {
  const float* x = (const float*)d_in[0];
  const float* w_qkv = (const float*)d_in[1];
  const float* w_out = (const float*)d_in[2];
  const float* b_out = (const float*)d_in[3];
  float* out = (float*)d_out;
  char* ws = (char*)d_ws;

  unsigned short* xb    = (unsigned short*)(ws + 0);         //  8 MB [8192][512]
  unsigned short* wqkvT = (unsigned short*)(ws + 8388608);   //  1.5 MB [1536][512]
  unsigned short* woutT = (unsigned short*)(ws + 9961472);   //  0.5 MB [512][512]
  unsigned short* qkvb  = (unsigned short*)(ws + 10485760);  // 24 MB [8192][1536]
  unsigned short* vtb   = (unsigned short*)(ws + 35651584);  //  8 MB [32][64][2048]
  unsigned short* Ob    = (unsigned short*)(ws + 44040192);  //  8 MB [8192][512]

  k_prep<<<2304, 256, 0, stream>>>(x, xb, w_qkv, wqkvT, w_out, woutT);
  k_gemm_bt<false, 128, true><<<dim3(12, 64), 256, 0, stream>>>(
      xb, wqkvT, (void*)qkvb, nullptr, vtb, 8192, 1536, 512);
  k_attn6<<<dim3(16, 32), 512, 0, stream>>>(qkvb, vtb, Ob);
  k_gemm_bt<true, 64, false><<<dim3(8, 64), 256, 0, stream>>>(
      Ob, woutT, (void*)out, b_out, nullptr, 8192, 512, 512);
}